// Round 21
// baseline (356.558 us; speedup 1.0000x reference)
//
#include <hip/hip_runtime.h>
#include <cstdint>
#include <cstddef>

typedef unsigned short u16;
typedef __attribute__((ext_vector_type(8))) short bf16x8;
typedef __attribute__((ext_vector_type(4))) float f32x4;
typedef __attribute__((address_space(1))) const unsigned int gu32;
typedef __attribute__((address_space(3))) unsigned int lu32;

#define QSCALE 0.1803368801111204f  // 0.125 * log2(e): softmax done in exp2 domain

__device__ __forceinline__ u16 f2bf(float f) {
  uint32_t u = __float_as_uint(f);
  u += 0x7fffu + ((u >> 16) & 1u);
  return (u16)(u >> 16);
}

// Bijective XCD-aware remap, bn-fast within each XCD chunk.
__device__ __forceinline__ void xcd_swz(int& bn, int& bm) {
  int gx = (int)gridDim.x;
  int n = gx * (int)gridDim.y;
  int lid = (int)blockIdx.x + gx * (int)blockIdx.y;
  int nid = (lid & 7) * (n >> 3) + (lid >> 3);
  bn = nid % gx;
  bm = nid / gx;
}

// ---------------- transpose fp32 (K,N) -> bf16 (N,K) ----------------
__global__ __launch_bounds__(256) void transpose_w(const float* __restrict__ W,
                                                   u16* __restrict__ WT,
                                                   int K, int N) {
  __shared__ float t[32][33];
  int n0 = blockIdx.x * 32, k0 = blockIdx.y * 32;
  for (int i = threadIdx.y; i < 32; i += 8)
    t[i][threadIdx.x] = W[(size_t)(k0 + i) * N + n0 + threadIdx.x];
  __syncthreads();
  for (int i = threadIdx.y; i < 32; i += 8)
    WT[(size_t)(n0 + i) * K + k0 + threadIdx.x] = f2bf(t[threadIdx.x][i]);
}

// merged 4x 1024x1024 transpose (Wq, Wk, Wv, Wo) in one launch
__global__ __launch_bounds__(256) void transpose_w4(
    const float* __restrict__ W0, const float* __restrict__ W1,
    const float* __restrict__ W2, const float* __restrict__ W3,
    u16* __restrict__ D0, u16* __restrict__ D1,
    u16* __restrict__ D2, u16* __restrict__ D3) {
  __shared__ float t[32][33];
  const float* W = (blockIdx.z == 0) ? W0 : (blockIdx.z == 1) ? W1
                   : (blockIdx.z == 2) ? W2 : W3;
  u16* D = (blockIdx.z == 0) ? D0 : (blockIdx.z == 1) ? D1
           : (blockIdx.z == 2) ? D2 : D3;
  int n0 = blockIdx.x * 32, k0 = blockIdx.y * 32;
  for (int i = threadIdx.y; i < 32; i += 8)
    t[i][threadIdx.x] = W[(size_t)(k0 + i) * 1024 + n0 + threadIdx.x];
  __syncthreads();
  for (int i = threadIdx.y; i < 32; i += 8)
    D[(size_t)(n0 + i) * 1024 + k0 + threadIdx.x] = f2bf(t[threadIdx.x][i]);
}

// ---------------- layernorm fp32 row(1024) -> bf16 ----------------
__global__ __launch_bounds__(256) void ln_kernel(const float* __restrict__ x,
                                                 const float* __restrict__ g,
                                                 const float* __restrict__ b,
                                                 u16* __restrict__ out) {
  int row = blockIdx.x;
  const float4 v = *(const float4*)(x + (size_t)row * 1024 + threadIdx.x * 4);
  float s = v.x + v.y + v.z + v.w;
  float ss = v.x * v.x + v.y * v.y + v.z * v.z + v.w * v.w;
#pragma unroll
  for (int d = 1; d < 64; d <<= 1) { s += __shfl_xor(s, d); ss += __shfl_xor(ss, d); }
  __shared__ float rs_[4], rss_[4];
  int wv = threadIdx.x >> 6;
  if ((threadIdx.x & 63) == 0) { rs_[wv] = s; rss_[wv] = ss; }
  __syncthreads();
  s = rs_[0] + rs_[1] + rs_[2] + rs_[3];
  ss = rss_[0] + rss_[1] + rss_[2] + rss_[3];
  float mu = s * (1.f / 1024.f);
  float var = ss * (1.f / 1024.f) - mu * mu;
  float rstd = rsqrtf(var + 1e-5f);
  float4 gv = *(const float4*)(g + threadIdx.x * 4);
  float4 bv = *(const float4*)(b + threadIdx.x * 4);
  uint32_t lo = (uint32_t)f2bf((v.x - mu) * rstd * gv.x + bv.x) |
                ((uint32_t)f2bf((v.y - mu) * rstd * gv.y + bv.y) << 16);
  uint32_t hi = (uint32_t)f2bf((v.z - mu) * rstd * gv.z + bv.z) |
                ((uint32_t)f2bf((v.w - mu) * rstd * gv.w + bv.w) << 16);
  uint2 o; o.x = lo; o.y = hi;
  *(uint2*)(out + (size_t)row * 1024 + threadIdx.x * 4) = o;
}

// ---------------- m97-structure GEMM: C = A(bf16 MxK) * BT(bf16 NxK) ----------------
// BM=BN=128 BK=64, 256 threads / 4 waves (2x2, 64x64 wave tiles), 16B-slot XOR
// swizzle (conflict-free ds_read_b128), ks-outer MFMA, bn-fast XCD remap.
// PIPE=0 (QKV, big grid): 32 KB single-buffer, multi-block residency overlaps.
// PIPE=1 (PROJ/FF1/FF2): 64 KB dbuf-2, {vmcnt(0); barrier; stage(t+1) || compute(t)}
//   -- loads of t+1 get a full compute phase to land; 1 barrier/iter.
// MODE 0: QKV (N=3072) -> Q2[B,T,1024]*QSCALE / K2[B,T,1024] / VT[B,H,HD,T]
// MODE 1: PROJ -> outf = acc + bias + resid      (fp32)
// MODE 2: FF1  -> ob0  = bf16(relu(acc + bias))
// MODE 3: FF2  -> outf = relu(acc + bias) + resid (fp32)
#define G128A(buf, t, is)                                                     \
  __builtin_amdgcn_global_load_lds(                                           \
      (gu32*)((const char*)(A + (size_t)(bm * 128 + (is) * 32 + srow) * K +   \
                            (size_t)(t) * 64) + ssw),                         \
      (lu32*)&lds[(buf) * 16384 + (is) * 2048 + wid * 512], 16, 0, 0)
#define G128B(buf, t, is)                                                     \
  __builtin_amdgcn_global_load_lds(                                           \
      (gu32*)((const char*)(BT + (size_t)(bn * 128 + (is) * 32 + srow) * K +  \
                            (size_t)(t) * 64) + ssw),                         \
      (lu32*)&lds[(buf) * 16384 + 8192 + (is) * 2048 + wid * 512], 16, 0, 0)
#define STAGE128(buf, t)                                                      \
  do {                                                                        \
    G128A(buf, t, 0); G128A(buf, t, 1); G128A(buf, t, 2); G128A(buf, t, 3);   \
    G128B(buf, t, 0); G128B(buf, t, 1); G128B(buf, t, 2); G128B(buf, t, 3);   \
  } while (0)

template <int MODE, int PIPE>
__global__ __launch_bounds__(256, 2) void g128(
    const u16* __restrict__ A, const u16* __restrict__ BT,
    int M, int N, int K,
    const float* __restrict__ bias, const float* __restrict__ resid,
    float* __restrict__ outf,
    u16* __restrict__ ob0, u16* __restrict__ ob1, u16* __restrict__ ob2) {
  __shared__ __align__(16) u16 lds[PIPE ? 32768 : 16384];  // 64 KB dbuf / 32 KB
  const int tid = threadIdx.x, lane = tid & 63, wid = tid >> 6;
  const int wr = wid >> 1, wc = wid & 1;  // 2x2 waves, wave tile 64x64
  int bn, bm;
  xcd_swz(bn, bm);
  const int l15 = lane & 15, lhi = lane >> 4;
  const int srow = tid >> 3;                              // 0..31
  const int ssw = ((tid & 7) * 16) ^ ((srow & 7) << 4);   // inverse-swizzled src byte
  const int swz = (l15 & 7) << 4;
  const int cb0 = (lhi * 16) ^ swz;                       // swizzled byte col, ks=0
  const int cb1 = (64 + lhi * 16) ^ swz;                  // ks=1

  f32x4 acc[4][4];
#pragma unroll
  for (int i = 0; i < 4; ++i)
#pragma unroll
    for (int j = 0; j < 4; ++j) acc[i][j] = (f32x4){0.f, 0.f, 0.f, 0.f};

  const int NT = K >> 6;

  if (PIPE) {
    STAGE128(0, 0);  // prologue: tile 0 -> buf 0
    for (int kt = 0; kt < NT; ++kt) {
      const int buf = kt & 1;
      asm volatile("s_waitcnt vmcnt(0)" ::: "memory");  // tile kt landed
      __syncthreads();  // visible to all waves; all waves done reading buf^1
      if (kt + 1 < NT) STAGE128(buf ^ 1, kt + 1);       // hide under compute(kt)
      const char* Ab = (const char*)lds + buf * 32768;
      const char* Bb = Ab + 16384;
#pragma unroll
      for (int ks = 0; ks < 2; ++ks) {
        const int cb = ks ? cb1 : cb0;
        bf16x8 af[4], bf[4];
#pragma unroll
        for (int mi = 0; mi < 4; ++mi)
          af[mi] = *(const bf16x8*)(Ab + (wr * 64 + mi * 16 + l15) * 128 + cb);
#pragma unroll
        for (int ni = 0; ni < 4; ++ni)
          bf[ni] = *(const bf16x8*)(Bb + (wc * 64 + ni * 16 + l15) * 128 + cb);
        __builtin_amdgcn_s_setprio(1);
#pragma unroll
        for (int mi = 0; mi < 4; ++mi)
#pragma unroll
          for (int ni = 0; ni < 4; ++ni)
            acc[mi][ni] = __builtin_amdgcn_mfma_f32_16x16x32_bf16(af[mi], bf[ni], acc[mi][ni], 0, 0, 0);
        __builtin_amdgcn_s_setprio(0);
      }
    }
  } else {
    for (int kt = 0; kt < NT; ++kt) {
      __syncthreads();   // prior tile's reads complete
      STAGE128(0, kt);
      __syncthreads();   // vmcnt drain + barrier: tile visible to all waves
      const char* Ab = (const char*)lds;
      const char* Bb = Ab + 16384;
#pragma unroll
      for (int ks = 0; ks < 2; ++ks) {
        const int cb = ks ? cb1 : cb0;
        bf16x8 af[4], bf[4];
#pragma unroll
        for (int mi = 0; mi < 4; ++mi)
          af[mi] = *(const bf16x8*)(Ab + (wr * 64 + mi * 16 + l15) * 128 + cb);
#pragma unroll
        for (int ni = 0; ni < 4; ++ni)
          bf[ni] = *(const bf16x8*)(Bb + (wc * 64 + ni * 16 + l15) * 128 + cb);
#pragma unroll
        for (int mi = 0; mi < 4; ++mi)
#pragma unroll
          for (int ni = 0; ni < 4; ++ni)
            acc[mi][ni] = __builtin_amdgcn_mfma_f32_16x16x32_bf16(af[mi], bf[ni], acc[mi][ni], 0, 0, 0);
      }
    }
  }

  // ---------------- LDS-staged coalesced epilogues (reuse the LDS buffer) --------
  char* ep = (char*)lds;
  if (MODE == 0 && bn >= 16) {
    // V -> VT[B,H,HD,T], 2 col-half passes: [64 col][264B pitch over 128 rows]
#pragma unroll
    for (int h = 0; h < 2; ++h) {
      __syncthreads();
      if (wc == h) {
#pragma unroll
        for (int mi = 0; mi < 4; ++mi)
#pragma unroll
          for (int ni = 0; ni < 4; ++ni) {
            uint32_t lo, hi;
            asm("v_cvt_pk_bf16_f32 %0, %1, %2"
                : "=v"(lo) : "v"(acc[mi][ni][0]), "v"(acc[mi][ni][1]));
            asm("v_cvt_pk_bf16_f32 %0, %1, %2"
                : "=v"(hi) : "v"(acc[mi][ni][2]), "v"(acc[mi][ni][3]));
            uint2 pk; pk.x = lo; pk.y = hi;
            int c_local = ni * 16 + l15;
            int rb = wr * 64 + mi * 16 + lhi * 4;
            *(uint2*)(ep + c_local * 264 + rb * 2) = pk;
          }
      }
      __syncthreads();
#pragma unroll
      for (int it = 0; it < 4; ++it) {
        int idx = it * 256 + tid;
        int c = idx >> 4, tc = idx & 15;
        uint4 d4 = *(const uint4*)(ep + c * 264 + tc * 16);
        int cm = bn * 128 + h * 64 + c - 2048, hh = cm >> 6, dd = cm & 63;
        size_t bh = (size_t)((bm >> 4) * 16 + hh);
        int t0 = (bm & 15) * 128;
        *(uint4*)&ob2[(bh * 64 + dd) * 2048 + t0 + tc * 8] = d4;
      }
    }
  } else if (MODE == 0 || MODE == 2) {
    // row-major bf16 (Q/K or FF1): 2 row-half passes [64 row][272B pitch]
    const float sc = (MODE == 0 && bn < 8) ? QSCALE : 1.f;
#pragma unroll
    for (int h = 0; h < 2; ++h) {
      __syncthreads();
      if (wr == h) {
#pragma unroll
        for (int mi = 0; mi < 4; ++mi)
#pragma unroll
          for (int ni = 0; ni < 4; ++ni) {
            int c_local = wc * 64 + ni * 16 + l15;
            int rb = mi * 16 + lhi * 4;
            float bv = (MODE == 2) ? bias[bn * 128 + c_local] : 0.f;
#pragma unroll
            for (int r = 0; r < 4; ++r) {
              float v = acc[mi][ni][r];
              v = (MODE == 2) ? fmaxf(v + bv, 0.f) : v * sc;
              *(u16*)(ep + (rb + r) * 272 + c_local * 2) = f2bf(v);
            }
          }
      }
      __syncthreads();
#pragma unroll
      for (int it = 0; it < 4; ++it) {
        int idx = it * 256 + tid;
        int row = idx >> 4, cc = idx & 15;
        uint4 d4 = *(const uint4*)(ep + row * 272 + cc * 16);
        size_t rg = (size_t)(bm * 128 + h * 64 + row);
        int colg = bn * 128 + cc * 8;
        if (MODE == 2) {
          *(uint4*)&ob0[rg * (size_t)N + colg] = d4;
        } else if (colg < 1024) {
          *(uint4*)&ob0[rg * 1024 + colg] = d4;          // Q2 (pre-scaled)
        } else {
          *(uint4*)&ob1[rg * 1024 + colg - 1024] = d4;   // K2
        }
      }
    }
  } else {
    // fp32 + bias + resid (PROJ/FF2): 4 quarter-passes [32 row][132 f32 pitch]
    float* epf = (float*)lds;
#pragma unroll
    for (int q = 0; q < 4; ++q) {
      __syncthreads();
      if (wr == (q >> 1)) {
#pragma unroll
        for (int mh = 0; mh < 2; ++mh) {
          int mi = (q & 1) * 2 + mh;
#pragma unroll
          for (int ni = 0; ni < 4; ++ni) {
            int c_local = wc * 64 + ni * 16 + l15;
            int rl = mh * 16 + lhi * 4;
#pragma unroll
            for (int r = 0; r < 4; ++r)
              epf[(rl + r) * 132 + c_local] = acc[mi][ni][r];
          }
        }
      }
      __syncthreads();
#pragma unroll
      for (int it = 0; it < 4; ++it) {
        int idx = it * 256 + tid;
        int row = idx >> 5, cc = idx & 31;
        float4 v = *(const float4*)&epf[row * 132 + cc * 4];
        int colg = bn * 128 + cc * 4;
        size_t rg = (size_t)(bm * 128 + q * 32 + row);
        float4 bv = *(const float4*)&bias[colg];
        float4 rv = *(const float4*)&resid[rg * (size_t)N + colg];
        float4 o4;
        if (MODE == 1) {
          o4.x = v.x + bv.x + rv.x; o4.y = v.y + bv.y + rv.y;
          o4.z = v.z + bv.z + rv.z; o4.w = v.w + bv.w + rv.w;
        } else {
          o4.x = fmaxf(v.x + bv.x, 0.f) + rv.x;
          o4.y = fmaxf(v.y + bv.y, 0.f) + rv.y;
          o4.z = fmaxf(v.z + bv.z, 0.f) + rv.z;
          o4.w = fmaxf(v.w + bv.w, 0.f) + rv.w;
        }
        *(float4*)&outf[rg * (size_t)N + colg] = o4;
      }
    }
  }
}

// ---------------- causal flash attention (R19 config, unchanged) ----------------
__global__ __launch_bounds__(512) void attn_kernel(
    const u16* __restrict__ Qb, const u16* __restrict__ Kb,
    const u16* __restrict__ VTb, u16* __restrict__ O) {
  const int lid = (int)blockIdx.x + 8 * (int)blockIdx.y;  // hw: xcd = lid & 7
  const int p = (lid >> 3) & 7;                           // 0..7
  const int bh = ((lid >> 6) << 3) | (lid & 7);           // same bh -> same XCD
  const int b = bh >> 4, h = bh & 15;
  const u16* Q = Qb + (size_t)b * 2048 * 1024 + h * 64;
  const u16* Kn = Kb + (size_t)b * 2048 * 1024 + h * 64;
  const u16* VT = VTb + (size_t)bh * 64 * 2048;
  const int tid = threadIdx.x, lane = tid & 63, wv = tid >> 6;
  const int l15 = lane & 15, lhi = lane >> 4;
  const int srow = tid >> 3;
  const int scol16 = (tid & 7) * 16;
  const int sw = scol16 ^ ((srow & 7) << 4);
  const int rswz = (l15 & 7) << 4;
  const int cb0 = (lhi * 16) ^ rswz;
  const int cb1 = (64 + lhi * 16) ^ rswz;

  __shared__ __align__(16) u16 KV[3][2][4096];  // ring-3: 48 KB
  __shared__ u16 Ps[8][16 * 72];                // 18 KB

  bf16x8 onesf;
#pragma unroll
  for (int i = 0; i < 8; ++i) onesf[i] = (short)0x3F80;  // bf16 1.0

#define STAGEKV(slot, kt)                                                     \
  do {                                                                        \
    __builtin_amdgcn_global_load_lds(                                         \
        (gu32*)((const char*)(Kn + (size_t)((kt)*64 + srow) * 1024) + sw),    \
        (lu32*)&KV[slot][0][wv * 512], 16, 0, 0);                             \
    __builtin_amdgcn_global_load_lds(                                         \
        (gu32*)((const char*)(VT + (size_t)srow * 2048 + (kt)*64) + sw),      \
        (lu32*)&KV[slot][1][wv * 512], 16, 0, 0);                             \
  } while (0)

#pragma unroll
  for (int pass = 0; pass < 2; ++pass) {
    const int chunk = pass ? p : (15 - p);
    const int qbase = chunk * 128 + wv * 16;
    const int nkt = 2 * chunk + 2;

    bf16x8 qf[2];
#pragma unroll
    for (int ks = 0; ks < 2; ++ks)
      qf[ks] = *(const bf16x8*)&Q[(size_t)(qbase + l15) * 1024 + ks * 32 + lhi * 8];

    f32x4 o[4];
#pragma unroll
    for (int f = 0; f < 4; ++f) o[f] = (f32x4){0.f, 0.f, 0.f, 0.f};
    f32x4 lacc = (f32x4){0.f, 0.f, 0.f, 0.f};

    __syncthreads();            // all waves done reading prior pass's LDS
    STAGEKV(0, 0);
    STAGEKV(1, 1);              // nkt >= 2 always

    for (int kt = 0; kt < nkt; ++kt) {
      if (kt + 1 < nkt) {
        asm volatile("s_waitcnt vmcnt(2)" ::: "memory");  // tile kt landed; kt+1 flying
      } else {
        asm volatile("s_waitcnt vmcnt(0)" ::: "memory");
      }
      __syncthreads();          // whole tile kt visible to all waves

      const int cs = kt % 3;
      if (kt * 64 <= qbase + 15) {
        const char* Kbase = (const char*)&KV[cs][0][0];
        const char* Vbase = (const char*)&KV[cs][1][0];

        f32x4 s[4];
#pragma unroll
        for (int jt = 0; jt < 4; ++jt) s[jt] = (f32x4){0.f, 0.f, 0.f, 0.f};
        __builtin_amdgcn_s_setprio(1);
#pragma unroll
        for (int ks = 0; ks < 2; ++ks) {
          const int cbyte = ks ? cb1 : cb0;
#pragma unroll
          for (int jt = 0; jt < 4; ++jt) {
            bf16x8 kf = *(const bf16x8*)(Kbase + (jt * 16 + l15) * 128 + cbyte);
            s[jt] = __builtin_amdgcn_mfma_f32_16x16x32_bf16(kf, qf[ks], s[jt], 0, 0, 0);
          }
        }
        __builtin_amdgcn_s_setprio(0);

        if (kt * 64 + 63 > qbase) {  // diagonal-crossing: causal mask
          int qg = qbase + l15;
#pragma unroll
          for (int jt = 0; jt < 4; ++jt)
#pragma unroll
            for (int r = 0; r < 4; ++r) {
              int kg = kt * 64 + jt * 16 + lhi * 4 + r;
              if (kg > qg) s[jt][r] = -1e30f;
            }
        }

        // max-free softmax: p = exp2(s); masked -> 0 exactly
#pragma unroll
        for (int jt = 0; jt < 4; ++jt)
#pragma unroll
          for (int r = 0; r < 4; ++r) s[jt][r] = exp2f(s[jt][r]);

#pragma unroll
        for (int jt = 0; jt < 4; ++jt) {
          uint32_t lo, hi;
          asm("v_cvt_pk_bf16_f32 %0, %1, %2"
              : "=v"(lo) : "v"(s[jt][0]), "v"(s[jt][1]));
          asm("v_cvt_pk_bf16_f32 %0, %1, %2"
              : "=v"(hi) : "v"(s[jt][2]), "v"(s[jt][3]));
          uint2 pk; pk.x = lo; pk.y = hi;
          *(uint2*)&Ps[wv][l15 * 72 + jt * 16 + lhi * 4] = pk;
        }
        __builtin_amdgcn_s_setprio(1);
#pragma unroll
        for (int ks = 0; ks < 2; ++ks) {
          const int cbyte = ks ? cb1 : cb0;
          bf16x8 pf = *(const bf16x8*)&Ps[wv][l15 * 72 + ks * 32 + lhi * 8];
          lacc = __builtin_amdgcn_mfma_f32_16x16x32_bf16(pf, onesf, lacc, 0, 0, 0);
#pragma unroll
          for (int f = 0; f < 4; ++f) {
            bf16x8 vfr = *(const bf16x8*)(Vbase + (f * 16 + l15) * 128 + cbyte);
            o[f] = __builtin_amdgcn_mfma_f32_16x16x32_bf16(pf, vfr, o[f], 0, 0, 0);
          }
        }
        __builtin_amdgcn_s_setprio(0);
      }

      if (kt + 2 < nkt) STAGEKV((kt + 2) % 3, kt + 2);
    }

    // epilogue: lacc broadcast across l15 (ones-B MFMA layout)
#pragma unroll
    for (int r = 0; r < 4; ++r) {
      float inv = 1.f / lacc[r];
      int t = qbase + lhi * 4 + r;
#pragma unroll
      for (int f = 0; f < 4; ++f)
        O[((size_t)(b * 2048 + t)) * 1024 + h * 64 + f * 16 + l15] = f2bf(o[f][r] * inv);
    }
  }
#undef STAGEKV
}

extern "C" void kernel_launch(void* const* d_in, const int* in_sizes, int n_in,
                              void* d_out, int out_size, void* d_ws, size_t ws_size,
                              hipStream_t stream) {
  const float* x   = (const float*)d_in[0];
  const float* Wq  = (const float*)d_in[1];
  const float* Wk  = (const float*)d_in[2];
  const float* Wv  = (const float*)d_in[3];
  const float* Wo  = (const float*)d_in[4];
  const float* bo  = (const float*)d_in[5];
  const float* W1  = (const float*)d_in[6];
  const float* b1  = (const float*)d_in[7];
  const float* W2  = (const float*)d_in[8];
  const float* b2  = (const float*)d_in[9];
  const float* g1  = (const float*)d_in[10];
  const float* be1 = (const float*)d_in[11];
  const float* g2  = (const float*)d_in[12];
  const float* be2 = (const float*)d_in[13];

  char* p = (char*)d_ws;
  auto alloc = [&](size_t bytes) {
    char* r = p;
    p += (bytes + 255) & ~(size_t)255;
    return r;
  };
  u16* WqkvT = (u16*)alloc(3072ull * 1024 * 2);
  u16* WoT   = (u16*)alloc(1024ull * 1024 * 2);
  u16* W1T   = (u16*)alloc(4096ull * 1024 * 2);
  u16* W2T   = (u16*)alloc(1024ull * 4096 * 2);
  u16* hln   = (u16*)alloc(8192ull * 1024 * 2);
  u16* Qbuf  = (u16*)alloc(8192ull * 1024 * 2);
  u16* Kbuf  = (u16*)alloc(8192ull * 1024 * 2);
  u16* VTbuf = (u16*)alloc(8192ull * 1024 * 2);
  float* x2  = (float*)alloc(8192ull * 1024 * 4);
  u16* ff1   = (u16*)alloc(8192ull * 4096 * 2);
  u16* Oattn = hln;   // hln dead after QKV GEMM
  u16* h2    = Qbuf;  // Qbuf dead after attention
  if ((size_t)(p - (char*)d_ws) > ws_size) return;

  dim3 tb(32, 8);
  transpose_w4<<<dim3(32, 32, 4), tb, 0, stream>>>(
      Wq, Wk, Wv, Wo, WqkvT, WqkvT + 1024 * 1024, WqkvT + 2048 * 1024, WoT);
  transpose_w<<<dim3(128, 32), tb, 0, stream>>>(W1, W1T, 1024, 4096);
  transpose_w<<<dim3(32, 128), tb, 0, stream>>>(W2, W2T, 4096, 1024);

  ln_kernel<<<8192, 256, 0, stream>>>(x, g1, be1, hln);

  g128<0, 0><<<dim3(24, 64), 256, 0, stream>>>(hln, WqkvT, 8192, 3072, 1024,
                                               nullptr, nullptr, nullptr,
                                               Qbuf, Kbuf, VTbuf);

  attn_kernel<<<dim3(8, 64), 512, 0, stream>>>(Qbuf, Kbuf, VTbuf, Oattn);

  g128<1, 1><<<dim3(8, 64), 256, 0, stream>>>(Oattn, WoT, 8192, 1024, 1024,
                                              bo, x, x2, nullptr, nullptr, nullptr);

  ln_kernel<<<8192, 256, 0, stream>>>(x2, g2, be2, h2);

  g128<2, 1><<<dim3(32, 64), 256, 0, stream>>>(h2, W1T, 8192, 4096, 1024,
                                               b1, nullptr, nullptr, ff1, nullptr, nullptr);

  g128<3, 1><<<dim3(8, 64), 256, 0, stream>>>(ff1, W2T, 8192, 1024, 4096,
                                              b2, x2, (float*)d_out, nullptr, nullptr, nullptr);
}

// Round 22
// 347.977 us; speedup vs baseline: 1.0247x; 1.0247x over previous
//
#include <hip/hip_runtime.h>
#include <cstdint>
#include <cstddef>

typedef unsigned short u16;
typedef __attribute__((ext_vector_type(8))) short bf16x8;
typedef __attribute__((ext_vector_type(4))) float f32x4;
typedef __attribute__((address_space(1))) const unsigned int gu32;
typedef __attribute__((address_space(3))) unsigned int lu32;

#define QSCALE 0.1803368801111204f  // 0.125 * log2(e): softmax done in exp2 domain

__device__ __forceinline__ u16 f2bf(float f) {
  uint32_t u = __float_as_uint(f);
  u += 0x7fffu + ((u >> 16) & 1u);
  return (u16)(u >> 16);
}

// Bijective XCD-aware remap, bn-fast within each XCD chunk.
__device__ __forceinline__ void xcd_swz(int& bn, int& bm) {
  int gx = (int)gridDim.x;
  int n = gx * (int)gridDim.y;
  int lid = (int)blockIdx.x + gx * (int)blockIdx.y;
  int nid = (lid & 7) * (n >> 3) + (lid >> 3);
  bn = nid % gx;
  bm = nid / gx;
}

// ---------------- transpose fp32 (K,N) -> bf16 (N,K) ----------------
__global__ __launch_bounds__(256) void transpose_w(const float* __restrict__ W,
                                                   u16* __restrict__ WT,
                                                   int K, int N) {
  __shared__ float t[32][33];
  int n0 = blockIdx.x * 32, k0 = blockIdx.y * 32;
  for (int i = threadIdx.y; i < 32; i += 8)
    t[i][threadIdx.x] = W[(size_t)(k0 + i) * N + n0 + threadIdx.x];
  __syncthreads();
  for (int i = threadIdx.y; i < 32; i += 8)
    WT[(size_t)(n0 + i) * K + k0 + threadIdx.x] = f2bf(t[threadIdx.x][i]);
}

// merged 4x 1024x1024 transpose (Wq, Wk, Wv, Wo) in one launch
__global__ __launch_bounds__(256) void transpose_w4(
    const float* __restrict__ W0, const float* __restrict__ W1,
    const float* __restrict__ W2, const float* __restrict__ W3,
    u16* __restrict__ D0, u16* __restrict__ D1,
    u16* __restrict__ D2, u16* __restrict__ D3) {
  __shared__ float t[32][33];
  const float* W = (blockIdx.z == 0) ? W0 : (blockIdx.z == 1) ? W1
                   : (blockIdx.z == 2) ? W2 : W3;
  u16* D = (blockIdx.z == 0) ? D0 : (blockIdx.z == 1) ? D1
           : (blockIdx.z == 2) ? D2 : D3;
  int n0 = blockIdx.x * 32, k0 = blockIdx.y * 32;
  for (int i = threadIdx.y; i < 32; i += 8)
    t[i][threadIdx.x] = W[(size_t)(k0 + i) * 1024 + n0 + threadIdx.x];
  __syncthreads();
  for (int i = threadIdx.y; i < 32; i += 8)
    D[(size_t)(n0 + i) * 1024 + k0 + threadIdx.x] = f2bf(t[threadIdx.x][i]);
}

// ---------------- layernorm fp32 row(1024) -> bf16 ----------------
__global__ __launch_bounds__(256) void ln_kernel(const float* __restrict__ x,
                                                 const float* __restrict__ g,
                                                 const float* __restrict__ b,
                                                 u16* __restrict__ out) {
  int row = blockIdx.x;
  const float4 v = *(const float4*)(x + (size_t)row * 1024 + threadIdx.x * 4);
  float s = v.x + v.y + v.z + v.w;
  float ss = v.x * v.x + v.y * v.y + v.z * v.z + v.w * v.w;
#pragma unroll
  for (int d = 1; d < 64; d <<= 1) { s += __shfl_xor(s, d); ss += __shfl_xor(ss, d); }
  __shared__ float rs_[4], rss_[4];
  int wv = threadIdx.x >> 6;
  if ((threadIdx.x & 63) == 0) { rs_[wv] = s; rss_[wv] = ss; }
  __syncthreads();
  s = rs_[0] + rs_[1] + rs_[2] + rs_[3];
  ss = rss_[0] + rss_[1] + rss_[2] + rss_[3];
  float mu = s * (1.f / 1024.f);
  float var = ss * (1.f / 1024.f) - mu * mu;
  float rstd = rsqrtf(var + 1e-5f);
  float4 gv = *(const float4*)(g + threadIdx.x * 4);
  float4 bv = *(const float4*)(b + threadIdx.x * 4);
  uint32_t lo = (uint32_t)f2bf((v.x - mu) * rstd * gv.x + bv.x) |
                ((uint32_t)f2bf((v.y - mu) * rstd * gv.y + bv.y) << 16);
  uint32_t hi = (uint32_t)f2bf((v.z - mu) * rstd * gv.z + bv.z) |
                ((uint32_t)f2bf((v.w - mu) * rstd * gv.w + bv.w) << 16);
  uint2 o; o.x = lo; o.y = hi;
  *(uint2*)(out + (size_t)row * 1024 + threadIdx.x * 4) = o;
}

// ---------------- m97-structure GEMM: C = A(bf16 MxK) * BT(bf16 NxK) ----------------
// BM=BN=128 BK=64, 256 threads / 4 waves (2x2, 64x64 wave tiles), 16B-slot XOR
// swizzle (conflict-free ds_read_b128), ks-outer MFMA, bn-fast XCD remap.
// PIPE=0 (QKV/FF1, big grids): 32 KB single-buffer, 4 blocks/CU overlap (L2-friendly).
// PIPE=1 (PROJ/FF2, grid=512 -> residency grid-limited to 2/CU): 64 KB dbuf-2,
//   {vmcnt(0); barrier; stage(t+1) || compute(t)} -- costs no occupancy here.
// MODE 0: QKV (N=3072) -> Q2[B,T,1024]*QSCALE / K2[B,T,1024] / VT[B,H,HD,T]
// MODE 1: PROJ -> outf = acc + bias + resid      (fp32)
// MODE 2: FF1  -> ob0  = bf16(relu(acc + bias))
// MODE 3: FF2  -> outf = relu(acc + bias) + resid (fp32)
#define G128A(buf, t, is)                                                     \
  __builtin_amdgcn_global_load_lds(                                           \
      (gu32*)((const char*)(A + (size_t)(bm * 128 + (is) * 32 + srow) * K +   \
                            (size_t)(t) * 64) + ssw),                         \
      (lu32*)&lds[(buf) * 16384 + (is) * 2048 + wid * 512], 16, 0, 0)
#define G128B(buf, t, is)                                                     \
  __builtin_amdgcn_global_load_lds(                                           \
      (gu32*)((const char*)(BT + (size_t)(bn * 128 + (is) * 32 + srow) * K +  \
                            (size_t)(t) * 64) + ssw),                         \
      (lu32*)&lds[(buf) * 16384 + 8192 + (is) * 2048 + wid * 512], 16, 0, 0)
#define STAGE128(buf, t)                                                      \
  do {                                                                        \
    G128A(buf, t, 0); G128A(buf, t, 1); G128A(buf, t, 2); G128A(buf, t, 3);   \
    G128B(buf, t, 0); G128B(buf, t, 1); G128B(buf, t, 2); G128B(buf, t, 3);   \
  } while (0)

template <int MODE, int PIPE>
__global__ __launch_bounds__(256, 2) void g128(
    const u16* __restrict__ A, const u16* __restrict__ BT,
    int M, int N, int K,
    const float* __restrict__ bias, const float* __restrict__ resid,
    float* __restrict__ outf,
    u16* __restrict__ ob0, u16* __restrict__ ob1, u16* __restrict__ ob2) {
  __shared__ __align__(16) u16 lds[PIPE ? 32768 : 16384];  // 64 KB dbuf / 32 KB
  const int tid = threadIdx.x, lane = tid & 63, wid = tid >> 6;
  const int wr = wid >> 1, wc = wid & 1;  // 2x2 waves, wave tile 64x64
  int bn, bm;
  xcd_swz(bn, bm);
  const int l15 = lane & 15, lhi = lane >> 4;
  const int srow = tid >> 3;                              // 0..31
  const int ssw = ((tid & 7) * 16) ^ ((srow & 7) << 4);   // inverse-swizzled src byte
  const int swz = (l15 & 7) << 4;
  const int cb0 = (lhi * 16) ^ swz;                       // swizzled byte col, ks=0
  const int cb1 = (64 + lhi * 16) ^ swz;                  // ks=1

  f32x4 acc[4][4];
#pragma unroll
  for (int i = 0; i < 4; ++i)
#pragma unroll
    for (int j = 0; j < 4; ++j) acc[i][j] = (f32x4){0.f, 0.f, 0.f, 0.f};

  const int NT = K >> 6;

  if (PIPE) {
    STAGE128(0, 0);  // prologue: tile 0 -> buf 0
    for (int kt = 0; kt < NT; ++kt) {
      const int buf = kt & 1;
      asm volatile("s_waitcnt vmcnt(0)" ::: "memory");  // tile kt landed
      __syncthreads();  // visible to all waves; all waves done reading buf^1
      if (kt + 1 < NT) STAGE128(buf ^ 1, kt + 1);       // hide under compute(kt)
      const char* Ab = (const char*)lds + buf * 32768;
      const char* Bb = Ab + 16384;
#pragma unroll
      for (int ks = 0; ks < 2; ++ks) {
        const int cb = ks ? cb1 : cb0;
        bf16x8 af[4], bf[4];
#pragma unroll
        for (int mi = 0; mi < 4; ++mi)
          af[mi] = *(const bf16x8*)(Ab + (wr * 64 + mi * 16 + l15) * 128 + cb);
#pragma unroll
        for (int ni = 0; ni < 4; ++ni)
          bf[ni] = *(const bf16x8*)(Bb + (wc * 64 + ni * 16 + l15) * 128 + cb);
        __builtin_amdgcn_s_setprio(1);
#pragma unroll
        for (int mi = 0; mi < 4; ++mi)
#pragma unroll
          for (int ni = 0; ni < 4; ++ni)
            acc[mi][ni] = __builtin_amdgcn_mfma_f32_16x16x32_bf16(af[mi], bf[ni], acc[mi][ni], 0, 0, 0);
        __builtin_amdgcn_s_setprio(0);
      }
    }
  } else {
    for (int kt = 0; kt < NT; ++kt) {
      __syncthreads();   // prior tile's reads complete
      STAGE128(0, kt);
      __syncthreads();   // vmcnt drain + barrier: tile visible to all waves
      const char* Ab = (const char*)lds;
      const char* Bb = Ab + 16384;
#pragma unroll
      for (int ks = 0; ks < 2; ++ks) {
        const int cb = ks ? cb1 : cb0;
        bf16x8 af[4], bf[4];
#pragma unroll
        for (int mi = 0; mi < 4; ++mi)
          af[mi] = *(const bf16x8*)(Ab + (wr * 64 + mi * 16 + l15) * 128 + cb);
#pragma unroll
        for (int ni = 0; ni < 4; ++ni)
          bf[ni] = *(const bf16x8*)(Bb + (wc * 64 + ni * 16 + l15) * 128 + cb);
#pragma unroll
        for (int mi = 0; mi < 4; ++mi)
#pragma unroll
          for (int ni = 0; ni < 4; ++ni)
            acc[mi][ni] = __builtin_amdgcn_mfma_f32_16x16x32_bf16(af[mi], bf[ni], acc[mi][ni], 0, 0, 0);
      }
    }
  }

  // ---------------- LDS-staged coalesced epilogues (reuse the LDS buffer) --------
  char* ep = (char*)lds;
  if (MODE == 0 && bn >= 16) {
    // V -> VT[B,H,HD,T], 2 col-half passes: [64 col][264B pitch over 128 rows]
#pragma unroll
    for (int h = 0; h < 2; ++h) {
      __syncthreads();
      if (wc == h) {
#pragma unroll
        for (int mi = 0; mi < 4; ++mi)
#pragma unroll
          for (int ni = 0; ni < 4; ++ni) {
            uint32_t lo, hi;
            asm("v_cvt_pk_bf16_f32 %0, %1, %2"
                : "=v"(lo) : "v"(acc[mi][ni][0]), "v"(acc[mi][ni][1]));
            asm("v_cvt_pk_bf16_f32 %0, %1, %2"
                : "=v"(hi) : "v"(acc[mi][ni][2]), "v"(acc[mi][ni][3]));
            uint2 pk; pk.x = lo; pk.y = hi;
            int c_local = ni * 16 + l15;
            int rb = wr * 64 + mi * 16 + lhi * 4;
            *(uint2*)(ep + c_local * 264 + rb * 2) = pk;
          }
      }
      __syncthreads();
#pragma unroll
      for (int it = 0; it < 4; ++it) {
        int idx = it * 256 + tid;
        int c = idx >> 4, tc = idx & 15;
        uint4 d4 = *(const uint4*)(ep + c * 264 + tc * 16);
        int cm = bn * 128 + h * 64 + c - 2048, hh = cm >> 6, dd = cm & 63;
        size_t bh = (size_t)((bm >> 4) * 16 + hh);
        int t0 = (bm & 15) * 128;
        *(uint4*)&ob2[(bh * 64 + dd) * 2048 + t0 + tc * 8] = d4;
      }
    }
  } else if (MODE == 0 || MODE == 2) {
    // row-major bf16 (Q/K or FF1): 2 row-half passes [64 row][272B pitch]
    const float sc = (MODE == 0 && bn < 8) ? QSCALE : 1.f;
#pragma unroll
    for (int h = 0; h < 2; ++h) {
      __syncthreads();
      if (wr == h) {
#pragma unroll
        for (int mi = 0; mi < 4; ++mi)
#pragma unroll
          for (int ni = 0; ni < 4; ++ni) {
            int c_local = wc * 64 + ni * 16 + l15;
            int rb = mi * 16 + lhi * 4;
            float bv = (MODE == 2) ? bias[bn * 128 + c_local] : 0.f;
#pragma unroll
            for (int r = 0; r < 4; ++r) {
              float v = acc[mi][ni][r];
              v = (MODE == 2) ? fmaxf(v + bv, 0.f) : v * sc;
              *(u16*)(ep + (rb + r) * 272 + c_local * 2) = f2bf(v);
            }
          }
      }
      __syncthreads();
#pragma unroll
      for (int it = 0; it < 4; ++it) {
        int idx = it * 256 + tid;
        int row = idx >> 4, cc = idx & 15;
        uint4 d4 = *(const uint4*)(ep + row * 272 + cc * 16);
        size_t rg = (size_t)(bm * 128 + h * 64 + row);
        int colg = bn * 128 + cc * 8;
        if (MODE == 2) {
          *(uint4*)&ob0[rg * (size_t)N + colg] = d4;
        } else if (colg < 1024) {
          *(uint4*)&ob0[rg * 1024 + colg] = d4;          // Q2 (pre-scaled)
        } else {
          *(uint4*)&ob1[rg * 1024 + colg - 1024] = d4;   // K2
        }
      }
    }
  } else {
    // fp32 + bias + resid (PROJ/FF2): 4 quarter-passes [32 row][132 f32 pitch]
    float* epf = (float*)lds;
#pragma unroll
    for (int q = 0; q < 4; ++q) {
      __syncthreads();
      if (wr == (q >> 1)) {
#pragma unroll
        for (int mh = 0; mh < 2; ++mh) {
          int mi = (q & 1) * 2 + mh;
#pragma unroll
          for (int ni = 0; ni < 4; ++ni) {
            int c_local = wc * 64 + ni * 16 + l15;
            int rl = mh * 16 + lhi * 4;
#pragma unroll
            for (int r = 0; r < 4; ++r)
              epf[(rl + r) * 132 + c_local] = acc[mi][ni][r];
          }
        }
      }
      __syncthreads();
#pragma unroll
      for (int it = 0; it < 4; ++it) {
        int idx = it * 256 + tid;
        int row = idx >> 5, cc = idx & 31;
        float4 v = *(const float4*)&epf[row * 132 + cc * 4];
        int colg = bn * 128 + cc * 4;
        size_t rg = (size_t)(bm * 128 + q * 32 + row);
        float4 bv = *(const float4*)&bias[colg];
        float4 rv = *(const float4*)&resid[rg * (size_t)N + colg];
        float4 o4;
        if (MODE == 1) {
          o4.x = v.x + bv.x + rv.x; o4.y = v.y + bv.y + rv.y;
          o4.z = v.z + bv.z + rv.z; o4.w = v.w + bv.w + rv.w;
        } else {
          o4.x = fmaxf(v.x + bv.x, 0.f) + rv.x;
          o4.y = fmaxf(v.y + bv.y, 0.f) + rv.y;
          o4.z = fmaxf(v.z + bv.z, 0.f) + rv.z;
          o4.w = fmaxf(v.w + bv.w, 0.f) + rv.w;
        }
        *(float4*)&outf[rg * (size_t)N + colg] = o4;
      }
    }
  }
}

// ---------------- causal flash attention (R19 config, unchanged) ----------------
__global__ __launch_bounds__(512) void attn_kernel(
    const u16* __restrict__ Qb, const u16* __restrict__ Kb,
    const u16* __restrict__ VTb, u16* __restrict__ O) {
  const int lid = (int)blockIdx.x + 8 * (int)blockIdx.y;  // hw: xcd = lid & 7
  const int p = (lid >> 3) & 7;                           // 0..7
  const int bh = ((lid >> 6) << 3) | (lid & 7);           // same bh -> same XCD
  const int b = bh >> 4, h = bh & 15;
  const u16* Q = Qb + (size_t)b * 2048 * 1024 + h * 64;
  const u16* Kn = Kb + (size_t)b * 2048 * 1024 + h * 64;
  const u16* VT = VTb + (size_t)bh * 64 * 2048;
  const int tid = threadIdx.x, lane = tid & 63, wv = tid >> 6;
  const int l15 = lane & 15, lhi = lane >> 4;
  const int srow = tid >> 3;
  const int scol16 = (tid & 7) * 16;
  const int sw = scol16 ^ ((srow & 7) << 4);
  const int rswz = (l15 & 7) << 4;
  const int cb0 = (lhi * 16) ^ rswz;
  const int cb1 = (64 + lhi * 16) ^ rswz;

  __shared__ __align__(16) u16 KV[3][2][4096];  // ring-3: 48 KB
  __shared__ u16 Ps[8][16 * 72];                // 18 KB

  bf16x8 onesf;
#pragma unroll
  for (int i = 0; i < 8; ++i) onesf[i] = (short)0x3F80;  // bf16 1.0

#define STAGEKV(slot, kt)                                                     \
  do {                                                                        \
    __builtin_amdgcn_global_load_lds(                                         \
        (gu32*)((const char*)(Kn + (size_t)((kt)*64 + srow) * 1024) + sw),    \
        (lu32*)&KV[slot][0][wv * 512], 16, 0, 0);                             \
    __builtin_amdgcn_global_load_lds(                                         \
        (gu32*)((const char*)(VT + (size_t)srow * 2048 + (kt)*64) + sw),      \
        (lu32*)&KV[slot][1][wv * 512], 16, 0, 0);                             \
  } while (0)

#pragma unroll
  for (int pass = 0; pass < 2; ++pass) {
    const int chunk = pass ? p : (15 - p);
    const int qbase = chunk * 128 + wv * 16;
    const int nkt = 2 * chunk + 2;

    bf16x8 qf[2];
#pragma unroll
    for (int ks = 0; ks < 2; ++ks)
      qf[ks] = *(const bf16x8*)&Q[(size_t)(qbase + l15) * 1024 + ks * 32 + lhi * 8];

    f32x4 o[4];
#pragma unroll
    for (int f = 0; f < 4; ++f) o[f] = (f32x4){0.f, 0.f, 0.f, 0.f};
    f32x4 lacc = (f32x4){0.f, 0.f, 0.f, 0.f};

    __syncthreads();            // all waves done reading prior pass's LDS
    STAGEKV(0, 0);
    STAGEKV(1, 1);              // nkt >= 2 always

    for (int kt = 0; kt < nkt; ++kt) {
      if (kt + 1 < nkt) {
        asm volatile("s_waitcnt vmcnt(2)" ::: "memory");  // tile kt landed; kt+1 flying
      } else {
        asm volatile("s_waitcnt vmcnt(0)" ::: "memory");
      }
      __syncthreads();          // whole tile kt visible to all waves

      const int cs = kt % 3;
      if (kt * 64 <= qbase + 15) {
        const char* Kbase = (const char*)&KV[cs][0][0];
        const char* Vbase = (const char*)&KV[cs][1][0];

        f32x4 s[4];
#pragma unroll
        for (int jt = 0; jt < 4; ++jt) s[jt] = (f32x4){0.f, 0.f, 0.f, 0.f};
        __builtin_amdgcn_s_setprio(1);
#pragma unroll
        for (int ks = 0; ks < 2; ++ks) {
          const int cbyte = ks ? cb1 : cb0;
#pragma unroll
          for (int jt = 0; jt < 4; ++jt) {
            bf16x8 kf = *(const bf16x8*)(Kbase + (jt * 16 + l15) * 128 + cbyte);
            s[jt] = __builtin_amdgcn_mfma_f32_16x16x32_bf16(kf, qf[ks], s[jt], 0, 0, 0);
          }
        }
        __builtin_amdgcn_s_setprio(0);

        if (kt * 64 + 63 > qbase) {  // diagonal-crossing: causal mask
          int qg = qbase + l15;
#pragma unroll
          for (int jt = 0; jt < 4; ++jt)
#pragma unroll
            for (int r = 0; r < 4; ++r) {
              int kg = kt * 64 + jt * 16 + lhi * 4 + r;
              if (kg > qg) s[jt][r] = -1e30f;
            }
        }

        // max-free softmax: p = exp2(s); masked -> 0 exactly
#pragma unroll
        for (int jt = 0; jt < 4; ++jt)
#pragma unroll
          for (int r = 0; r < 4; ++r) s[jt][r] = exp2f(s[jt][r]);

#pragma unroll
        for (int jt = 0; jt < 4; ++jt) {
          uint32_t lo, hi;
          asm("v_cvt_pk_bf16_f32 %0, %1, %2"
              : "=v"(lo) : "v"(s[jt][0]), "v"(s[jt][1]));
          asm("v_cvt_pk_bf16_f32 %0, %1, %2"
              : "=v"(hi) : "v"(s[jt][2]), "v"(s[jt][3]));
          uint2 pk; pk.x = lo; pk.y = hi;
          *(uint2*)&Ps[wv][l15 * 72 + jt * 16 + lhi * 4] = pk;
        }
        __builtin_amdgcn_s_setprio(1);
#pragma unroll
        for (int ks = 0; ks < 2; ++ks) {
          const int cbyte = ks ? cb1 : cb0;
          bf16x8 pf = *(const bf16x8*)&Ps[wv][l15 * 72 + ks * 32 + lhi * 8];
          lacc = __builtin_amdgcn_mfma_f32_16x16x32_bf16(pf, onesf, lacc, 0, 0, 0);
#pragma unroll
          for (int f = 0; f < 4; ++f) {
            bf16x8 vfr = *(const bf16x8*)(Vbase + (f * 16 + l15) * 128 + cbyte);
            o[f] = __builtin_amdgcn_mfma_f32_16x16x32_bf16(pf, vfr, o[f], 0, 0, 0);
          }
        }
        __builtin_amdgcn_s_setprio(0);
      }

      if (kt + 2 < nkt) STAGEKV((kt + 2) % 3, kt + 2);
    }

    // epilogue: lacc broadcast across l15 (ones-B MFMA layout)
#pragma unroll
    for (int r = 0; r < 4; ++r) {
      float inv = 1.f / lacc[r];
      int t = qbase + lhi * 4 + r;
#pragma unroll
      for (int f = 0; f < 4; ++f)
        O[((size_t)(b * 2048 + t)) * 1024 + h * 64 + f * 16 + l15] = f2bf(o[f][r] * inv);
    }
  }
#undef STAGEKV
}

extern "C" void kernel_launch(void* const* d_in, const int* in_sizes, int n_in,
                              void* d_out, int out_size, void* d_ws, size_t ws_size,
                              hipStream_t stream) {
  const float* x   = (const float*)d_in[0];
  const float* Wq  = (const float*)d_in[1];
  const float* Wk  = (const float*)d_in[2];
  const float* Wv  = (const float*)d_in[3];
  const float* Wo  = (const float*)d_in[4];
  const float* bo  = (const float*)d_in[5];
  const float* W1  = (const float*)d_in[6];
  const float* b1  = (const float*)d_in[7];
  const float* W2  = (const float*)d_in[8];
  const float* b2  = (const float*)d_in[9];
  const float* g1  = (const float*)d_in[10];
  const float* be1 = (const float*)d_in[11];
  const float* g2  = (const float*)d_in[12];
  const float* be2 = (const float*)d_in[13];

  char* p = (char*)d_ws;
  auto alloc = [&](size_t bytes) {
    char* r = p;
    p += (bytes + 255) & ~(size_t)255;
    return r;
  };
  u16* WqkvT = (u16*)alloc(3072ull * 1024 * 2);
  u16* WoT   = (u16*)alloc(1024ull * 1024 * 2);
  u16* W1T   = (u16*)alloc(4096ull * 1024 * 2);
  u16* W2T   = (u16*)alloc(1024ull * 4096 * 2);
  u16* hln   = (u16*)alloc(8192ull * 1024 * 2);
  u16* Qbuf  = (u16*)alloc(8192ull * 1024 * 2);
  u16* Kbuf  = (u16*)alloc(8192ull * 1024 * 2);
  u16* VTbuf = (u16*)alloc(8192ull * 1024 * 2);
  float* x2  = (float*)alloc(8192ull * 1024 * 4);
  u16* ff1   = (u16*)alloc(8192ull * 4096 * 2);
  u16* Oattn = hln;   // hln dead after QKV GEMM
  u16* h2    = Qbuf;  // Qbuf dead after attention
  if ((size_t)(p - (char*)d_ws) > ws_size) return;

  dim3 tb(32, 8);
  transpose_w4<<<dim3(32, 32, 4), tb, 0, stream>>>(
      Wq, Wk, Wv, Wo, WqkvT, WqkvT + 1024 * 1024, WqkvT + 2048 * 1024, WoT);
  transpose_w<<<dim3(128, 32), tb, 0, stream>>>(W1, W1T, 1024, 4096);
  transpose_w<<<dim3(32, 128), tb, 0, stream>>>(W2, W2T, 4096, 1024);

  ln_kernel<<<8192, 256, 0, stream>>>(x, g1, be1, hln);

  g128<0, 0><<<dim3(24, 64), 256, 0, stream>>>(hln, WqkvT, 8192, 3072, 1024,
                                               nullptr, nullptr, nullptr,
                                               Qbuf, Kbuf, VTbuf);

  attn_kernel<<<dim3(8, 64), 512, 0, stream>>>(Qbuf, Kbuf, VTbuf, Oattn);

  g128<1, 1><<<dim3(8, 64), 256, 0, stream>>>(Oattn, WoT, 8192, 1024, 1024,
                                              bo, x, x2, nullptr, nullptr, nullptr);

  ln_kernel<<<8192, 256, 0, stream>>>(x2, g2, be2, h2);

  g128<2, 0><<<dim3(32, 64), 256, 0, stream>>>(h2, W1T, 8192, 4096, 1024,
                                               b1, nullptr, nullptr, ff1, nullptr, nullptr);

  g128<3, 1><<<dim3(8, 64), 256, 0, stream>>>(ff1, W2T, 8192, 1024, 4096,
                                              b2, x2, (float*)d_out, nullptr, nullptr, nullptr);
}